// Round 5
// baseline (310.015 us; speedup 1.0000x reference)
//
#include <hip/hip_runtime.h>
#include <stdint.h>

typedef __bf16 bf16_t;
typedef __bf16 bf16x8 __attribute__((ext_vector_type(8)));
typedef float f32x4 __attribute__((ext_vector_type(4)));
typedef unsigned short us16x8 __attribute__((ext_vector_type(8)));

#define MFMA16(a, b, c) __builtin_amdgcn_mfma_f32_16x16x32_bf16(a, b, c, 0, 0, 0)
#define BAR() __builtin_amdgcn_s_barrier()
#define PRIO1() __builtin_amdgcn_s_setprio(1)
#define PRIO0() __builtin_amdgcn_s_setprio(0)
#define LGKM0()                                        \
  do {                                                 \
    asm volatile("s_waitcnt lgkmcnt(0)" ::: "memory"); \
    __builtin_amdgcn_sched_barrier(0);                 \
  } while (0)
#define VMCNT(n)                                          \
  do {                                                    \
    asm volatile("s_waitcnt vmcnt(" #n ")" ::: "memory"); \
    __builtin_amdgcn_sched_barrier(0);                    \
  } while (0)

__device__ __forceinline__ void stage16(const bf16_t* g, bf16_t* l) {
  __builtin_amdgcn_global_load_lds((__attribute__((address_space(1))) void*)g,
                                   (__attribute__((address_space(3))) void*)l, 16, 0, 0);
}

// ---------------- f32 -> bf16 conversion ----------------
__global__ __launch_bounds__(256) void cvt_f32_to_bf16(const float* __restrict__ in,
                                                       bf16_t* __restrict__ out, int n8) {
  int i = blockIdx.x * 256 + threadIdx.x;
  if (i >= n8) return;
  const f32x4* p = (const f32x4*)(in + (size_t)i * 8);
  f32x4 a = p[0], b = p[1];
  bf16x8 o;
  o[0] = (bf16_t)a[0]; o[1] = (bf16_t)a[1]; o[2] = (bf16_t)a[2]; o[3] = (bf16_t)a[3];
  o[4] = (bf16_t)b[0]; o[5] = (bf16_t)b[1]; o[6] = (bf16_t)b[2]; o[7] = (bf16_t)b[3];
  *(bf16x8*)(out + (size_t)i * 8) = o;
}

// ============ 256x128-tile 2-phase NT GEMM (counted vmcnt, deep prefetch) ============
// C[M,N] = A[M,K]*B[N,K]^T + bias. 512 thr = 8 waves (4M x 2N), wave tile 64x64,
// acc[4][4]. BK=64 split as 2 k-halves of 32. LDS [buf][kh][rows][32]:
// SA 2*2*256*32 (64 KiB) + SB 2*2*128*32 (32 KiB) = 96 KiB -> grid rounds of 256 CUs.
// Per phase (one k-half): 8 ds_read_b128 + 3 global_load_lds + 16 MFMA.
// Issue schedule: t.Ph1 stages kh1(t+1)->buf^1 (kh1 of buf^1 dead since t-1.Ph2);
//                 t.Ph2 stages kh0(t+2)->buf   (kh0 of buf dead after t.Ph1).
// Uniform VMCNT(6) each phase: 3 loads/phase -> waits the batch issued 2 phases ago,
// exactly what the NEXT phase reads. Never drains to 0 in the loop.
// LDS swizzle: 4 16B-blocks/row, blk ^= (row>>1)&3 -> uniform 8 lanes/bank-quad (free).
// Grid: bn-major within XCD chunks -> per-XCD B-panel ~3 MB (L2-resident).
template <int OUT_BF16>
__global__ __launch_bounds__(512, 2) void gemm_nt_p2(const bf16_t* __restrict__ A,
                                                     const bf16_t* __restrict__ B,
                                                     const float* __restrict__ bias,
                                                     void* __restrict__ Cout,
                                                     int M, int N, int K) {
  __shared__ bf16_t SA[2 * 2 * 256 * 32];
  __shared__ bf16_t SB[2 * 2 * 128 * 32];
  const int tid = threadIdx.x;
  const int l = tid & 63, w = tid >> 6;
  const int l15 = l & 15, l4 = l >> 4;  // l4 in 0..3 = k-subblock
  const int wm = w >> 1, wn = w & 1;
  const int nbm = M >> 8;
  const int nwg = gridDim.x;
  const int bid = blockIdx.x;
  const int wg = (bid & 7) * (nwg >> 3) + (bid >> 3);  // XCD chunks (nwg % 8 == 0)
  const int bn = wg / nbm, bm = wg % nbm;              // bn-major inside a chunk

  // ---- staging source addresses (pre-swizzled global cols) ----
  const int sA0 = tid, sA1 = 512 + tid;
  const int rA0 = sA0 >> 2, rA1 = sA1 >> 2, rB = tid >> 2;
  const int cA0 = ((sA0 & 3) ^ ((rA0 >> 1) & 3)) << 3;
  const int cA1 = ((sA1 & 3) ^ ((rA1 >> 1) & 3)) << 3;
  const int cB = ((tid & 3) ^ ((rB >> 1) & 3)) << 3;
  const bf16_t* gA0 = A + (size_t)(bm * 256 + rA0) * K + cA0;
  const bf16_t* gA1 = A + (size_t)(bm * 256 + rA1) * K + cA1;
  const bf16_t* gB = B + (size_t)(bn * 128 + rB) * K + cB;

  // ---- swizzled read offsets (per k-half region) ----
  int aoff[4], boff[4];
#pragma unroll
  for (int mi = 0; mi < 4; ++mi) {
    int r = wm * 64 + mi * 16 + l15;
    aoff[mi] = r * 32 + ((l4 ^ ((r >> 1) & 3)) << 3);
  }
#pragma unroll
  for (int ni = 0; ni < 4; ++ni) {
    int r = wn * 64 + ni * 16 + l15;
    boff[ni] = r * 32 + ((l4 ^ ((r >> 1) & 3)) << 3);
  }

  f32x4 acc[4][4] = {};

  auto STAGE = [&](int tau, int h, int buf) {
    const int koff = tau * 64 + h * 32;
    stage16(gA0 + koff, SA + buf * 16384 + h * 8192 + sA0 * 8);
    stage16(gA1 + koff, SA + buf * 16384 + h * 8192 + sA1 * 8);
    stage16(gB + koff, SB + buf * 8192 + h * 4096 + tid * 8);
  };

  auto PHASE = [&](int buf, int h, int tauS, int hS, int bufS) {
    bf16x8 aR[4], bR[4];
#pragma unroll
    for (int mi = 0; mi < 4; ++mi)
      aR[mi] = *(const bf16x8*)(SA + buf * 16384 + h * 8192 + aoff[mi]);
#pragma unroll
    for (int ni = 0; ni < 4; ++ni)
      bR[ni] = *(const bf16x8*)(SB + buf * 8192 + h * 4096 + boff[ni]);
    STAGE(tauS, hS, bufS);
    VMCNT(6);
    BAR();
    LGKM0();
    PRIO1();
#pragma unroll
    for (int mi = 0; mi < 4; ++mi)
#pragma unroll
      for (int ni = 0; ni < 4; ++ni) acc[mi][ni] = MFMA16(aR[mi], bR[ni], acc[mi][ni]);
    PRIO0();
    BAR();
  };

  const int nk = K >> 6;  // even (K=2048 -> 32)
  // ---- prologue: kh0(0),kh1(0)->buf0; kh0(1)->buf1; keep 6 in flight ----
  STAGE(0, 0, 0);
  STAGE(0, 1, 0);
  STAGE(1, 0, 1);
  VMCNT(6);
  BAR();

  for (int t = 0; t < nk; t += 2) {
    const int t1a = (t + 1 < nk) ? t + 1 : nk - 1;
    const int t2a = (t + 2 < nk) ? t + 2 : nk - 1;
    const int t3a = (t + 3 < nk) ? t + 3 : nk - 1;
    // tile t (cur buf 0)
    PHASE(0, 0, t1a, 1, 1);  // read kh0(t); stage kh1(t+1)->buf1
    PHASE(0, 1, t2a, 0, 0);  // read kh1(t); stage kh0(t+2)->buf0
    // tile t+1 (cur buf 1)
    PHASE(1, 0, t2a, 1, 0);  // read kh0(t+1); stage kh1(t+2)->buf0
    PHASE(1, 1, t3a, 0, 1);  // read kh1(t+1); stage kh0(t+3)->buf1
  }
  VMCNT(0);

  // ---- epilogue ----
  const int rbase = bm * 256 + wm * 64 + (l4 << 2);
  const int cbase = bn * 128 + wn * 64 + l15;
#pragma unroll
  for (int ni = 0; ni < 4; ++ni) {
    float bv = bias[cbase + ni * 16];
#pragma unroll
    for (int mi = 0; mi < 4; ++mi)
#pragma unroll
      for (int r = 0; r < 4; ++r) {
        float v = acc[mi][ni][r] + bv;
        size_t off = (size_t)(rbase + mi * 16 + r) * N + (cbase + ni * 16);
        if (OUT_BF16) ((bf16_t*)Cout)[off] = (bf16_t)v;
        else ((float*)Cout)[off] = v;
      }
  }
}

// ---------------- causal flash attention (unchanged) ----------------
__global__ __launch_bounds__(256, 2) void attn_fwd(const bf16_t* __restrict__ qkv,
                                                   bf16_t* __restrict__ att) {
  __shared__ bf16_t Kt[64 * 128];
  __shared__ bf16_t Vt[128 * 64];
  __shared__ bf16_t Pw[4][16 * 64];

  int bid = blockIdx.x;
  int pair = bid >> 5, bh = bid & 31;
  int h = bh & 15, b = bh >> 4;
  int tid = threadIdx.x;
  int l = tid & 63, w = tid >> 6;
  int l15 = l & 15, l4 = l >> 4, l7 = l & 7;
  const size_t LD = 6144;
  const bf16_t* base = qkv + (size_t)b * 2048 * LD;

#pragma unroll 1
  for (int phase = 0; phase < 2; ++phase) {
    int qt = phase ? 31 - pair : pair;
    int q0 = qt << 6;
    int wq0 = q0 + w * 16;

    bf16x8 qf[4];
#pragma unroll
    for (int kk = 0; kk < 4; ++kk)
      qf[kk] = *(const bf16x8*)(base + (size_t)(wq0 + l15) * LD + h * 128 + kk * 32 + l4 * 8);

    f32x4 acc[8] = {};
    float mrow[4], lrow[4];
#pragma unroll
    for (int r = 0; r < 4; ++r) { mrow[r] = -1e30f; lrow[r] = 0.f; }

    int nkt = qt + 1;
    for (int kt = 0; kt < nkt; ++kt) {
      int kb = kt << 6;
      const bf16_t* vg = base + (size_t)kb * LD + 4096 + h * 128;
      us16x8 va[2], vb[2];
#pragma unroll
      for (int p = 0; p < 2; ++p) {
        int g = p * 256 + tid;
        int kv = (g >> 4) << 1;
        int d0 = (g & 15) << 3;
        va[p] = *(const us16x8*)(vg + (size_t)kv * LD + d0);
        vb[p] = *(const us16x8*)(vg + (size_t)(kv + 1) * LD + d0);
      }
      const bf16_t* kg = base + (size_t)kb * LD + 2048 + h * 128;
#pragma unroll
      for (int i = 0; i < 4; ++i) {
        int e = i * 256 + tid;
        int row = e >> 4, blk = e & 15;
        int src = (blk ^ (row & 7)) << 3;
        stage16(kg + (size_t)row * LD + src, Kt + e * 8);
      }
#pragma unroll
      for (int p = 0; p < 2; ++p) {
        int g = p * 256 + tid;
        int kv = (g >> 4) << 1;
        int d0 = (g & 15) << 3;
        int k8 = kv >> 3, kr = kv & 7;
#pragma unroll
        for (int j = 0; j < 8; ++j) {
          int d = d0 + j;
          int swz = k8 ^ ((d ^ (d >> 3)) & 7);
          unsigned pack = (unsigned)va[p][j] | ((unsigned)vb[p][j] << 16);
          *(unsigned*)(&Vt[d * 64 + swz * 8 + kr]) = pack;
        }
      }
      __syncthreads();

      {
        f32x4 s[4] = {};
        __builtin_amdgcn_s_setprio(1);
#pragma unroll
        for (int kk = 0; kk < 4; ++kk) {
          int blk = (kk * 4 + l4) ^ l7;
#pragma unroll
          for (int n = 0; n < 4; ++n) {
            bf16x8 kf = *(const bf16x8*)(Kt + (n * 16 + l15) * 128 + blk * 8);
            s[n] = MFMA16(qf[kk], kf, s[n]);
          }
        }
        __builtin_amdgcn_s_setprio(0);

        const float sc = 0.08838834764831845f;
        bool needMask = (kb + 63) > wq0;
        float scf[4];
#pragma unroll
        for (int r = 0; r < 4; ++r) {
          int q = wq0 + (l4 << 2) + r;
#pragma unroll
          for (int n = 0; n < 4; ++n) {
            float v = s[n][r] * sc;
            if (needMask && (kb + n * 16 + l15) > q) v = -1e30f;
            s[n][r] = v;
          }
          float mx = fmaxf(fmaxf(s[0][r], s[1][r]), fmaxf(s[2][r], s[3][r]));
          mx = fmaxf(mx, __shfl_xor(mx, 1));
          mx = fmaxf(mx, __shfl_xor(mx, 2));
          mx = fmaxf(mx, __shfl_xor(mx, 4));
          mx = fmaxf(mx, __shfl_xor(mx, 8));
          float mn = fmaxf(mrow[r], mx);
          float sf = __expf(mrow[r] - mn);
          mrow[r] = mn;
          scf[r] = sf;
          float rs = 0.f;
#pragma unroll
          for (int n = 0; n < 4; ++n) {
            float pv = __expf(s[n][r] - mn);
            s[n][r] = pv;
            rs += pv;
          }
          rs += __shfl_xor(rs, 1);
          rs += __shfl_xor(rs, 2);
          rs += __shfl_xor(rs, 4);
          rs += __shfl_xor(rs, 8);
          lrow[r] = lrow[r] * sf + rs;
        }
#pragma unroll
        for (int nd = 0; nd < 8; ++nd)
#pragma unroll
          for (int r = 0; r < 4; ++r)
            acc[nd][r] *= scf[r];
#pragma unroll
        for (int n = 0; n < 4; ++n) {
          int cb8 = n * 2 + (l15 >> 3);
#pragma unroll
          for (int r = 0; r < 4; ++r) {
            int row = (l4 << 2) + r;
            Pw[w][row * 64 + ((cb8 ^ (row & 7)) << 3) + l7] = (bf16_t)s[n][r];
          }
        }
        __builtin_amdgcn_s_setprio(1);
#pragma unroll
        for (int kk2 = 0; kk2 < 2; ++kk2) {
          bf16x8 pa = *(const bf16x8*)(&Pw[w][l15 * 64 + (((kk2 * 4 + l4) ^ l7) << 3)]);
#pragma unroll
          for (int nd = 0; nd < 8; ++nd) {
            int d = nd * 16 + l15;
            int swz = (kk2 * 4 + l4) ^ ((d ^ (d >> 3)) & 7);
            bf16x8 bv = *(const bf16x8*)(&Vt[d * 64 + swz * 8]);
            acc[nd] = MFMA16(pa, bv, acc[nd]);
          }
        }
        __builtin_amdgcn_s_setprio(0);
      }
      __syncthreads();
    }

#pragma unroll
    for (int r = 0; r < 4; ++r) {
      float inv = 1.0f / lrow[r];
      size_t ro = (size_t)(b * 2048 + wq0 + (l4 << 2) + r) * 2048 + h * 128;
#pragma unroll
      for (int nd = 0; nd < 8; ++nd)
        att[ro + nd * 16 + l15] = (bf16_t)(acc[nd][r] * inv);
    }
  }
}

// ---------------- launch ----------------
extern "C" void kernel_launch(void* const* d_in, const int* in_sizes, int n_in,
                              void* d_out, int out_size, void* d_ws, size_t ws_size,
                              hipStream_t stream) {
  (void)in_sizes; (void)n_in; (void)out_size; (void)ws_size;
  const float* x = (const float*)d_in[0];
  const float* w_attn = (const float*)d_in[1];
  const float* b_attn = (const float*)d_in[2];
  const float* w_proj = (const float*)d_in[3];
  const float* b_proj = (const float*)d_in[4];
  float* out = (float*)d_out;

  char* ws = (char*)d_ws;
  bf16_t* xb  = (bf16_t*)(ws);
  bf16_t* wab = (bf16_t*)(ws + 16777216);
  bf16_t* wpb = (bf16_t*)(ws + 41943040);
  bf16_t* qkv = (bf16_t*)(ws + 50331648);
  bf16_t* att = xb;  // xb dead after GEMM1

  cvt_f32_to_bf16<<<4096, 256, 0, stream>>>(x, xb, 1048576);
  cvt_f32_to_bf16<<<6144, 256, 0, stream>>>(w_attn, wab, 1572864);
  cvt_f32_to_bf16<<<2048, 256, 0, stream>>>(w_proj, wpb, 524288);

  // qkv = x @ w_attn^T + b_attn -> bf16 [4096, 6144]  (256x128 tiles: 768 = 3 rounds)
  gemm_nt_p2<1><<<768, 512, 0, stream>>>(xb, wab, b_attn, qkv, 4096, 6144, 2048);

  // causal flash attention -> att bf16 [4096, 2048]
  attn_fwd<<<512, 256, 0, stream>>>(qkv, att);

  // out = att @ w_proj^T + b_proj -> f32 [4096, 2048]  (256x128 tiles: 256 = 1 round)
  gemm_nt_p2<0><<<256, 512, 0, stream>>>(att, wpb, b_proj, out, 4096, 2048, 2048);
}

// Round 6
// 295.189 us; speedup vs baseline: 1.0502x; 1.0502x over previous
//
#include <hip/hip_runtime.h>
#include <stdint.h>

typedef __bf16 bf16_t;
typedef __bf16 bf16x8 __attribute__((ext_vector_type(8)));
typedef float f32x4 __attribute__((ext_vector_type(4)));
typedef unsigned short us16x8 __attribute__((ext_vector_type(8)));

#define MFMA16(a, b, c) __builtin_amdgcn_mfma_f32_16x16x32_bf16(a, b, c, 0, 0, 0)
#define BAR() __builtin_amdgcn_s_barrier()
#define PRIO1() __builtin_amdgcn_s_setprio(1)
#define PRIO0() __builtin_amdgcn_s_setprio(0)
#define LGKM0()                                        \
  do {                                                 \
    asm volatile("s_waitcnt lgkmcnt(0)" ::: "memory"); \
    __builtin_amdgcn_sched_barrier(0);                 \
  } while (0)
#define VMCNT(n)                                          \
  do {                                                    \
    asm volatile("s_waitcnt vmcnt(" #n ")" ::: "memory"); \
    __builtin_amdgcn_sched_barrier(0);                    \
  } while (0)

__device__ __forceinline__ void stage16(const bf16_t* g, bf16_t* l) {
  __builtin_amdgcn_global_load_lds((__attribute__((address_space(1))) void*)g,
                                   (__attribute__((address_space(3))) void*)l, 16, 0, 0);
}

// ---------------- f32 -> bf16 conversion ----------------
__global__ __launch_bounds__(256) void cvt_f32_to_bf16(const float* __restrict__ in,
                                                       bf16_t* __restrict__ out, int n8) {
  int i = blockIdx.x * 256 + threadIdx.x;
  if (i >= n8) return;
  const f32x4* p = (const f32x4*)(in + (size_t)i * 8);
  f32x4 a = p[0], b = p[1];
  bf16x8 o;
  o[0] = (bf16_t)a[0]; o[1] = (bf16_t)a[1]; o[2] = (bf16_t)a[2]; o[3] = (bf16_t)a[3];
  o[4] = (bf16_t)b[0]; o[5] = (bf16_t)b[1]; o[6] = (bf16_t)b[2]; o[7] = (bf16_t)b[3];
  *(bf16x8*)(out + (size_t)i * 8) = o;
}

// ======== 128x128-tile BK=32 4-phase NT GEMM, counted vmcnt, 3 blocks/CU ========
// C[M,N] = A[M,K]*B[N,K]^T + bias. 256 thr = 4 waves (2Mx2N), wave 64x64, acc[4][4].
// LDS: SA[2buf][2half][64][32] + SB same = 32 KB -> 3 blocks/CU (launch_bounds 256,3).
// Per K-tile-32, 4 phases (quadrants of the 2x2 frag-halves):
//  Ph1: read aR(mi0,1)+bR(ni0,1)              -> MFMA acc[0..1][0..1]
//  Ph2: read bR(ni2,3)                        -> MFMA acc[0..1][2..3]
//  Ph3: read aR(mi2,3); stage B(t+2) (2 ld)   -> MFMA acc[2..3][2..3]
//  Ph4: stage A(t+2) (2 ld); VMCNT(4)         -> MFMA acc[2..3][0..1]
// Liveness: A-halves read Ph1+Ph3 -> dead at Ph4's issue window (post Ph3-endBAR);
// B-halves read Ph1+Ph2 -> dead at Ph3's window. One VMCNT(4) per tile at Ph4:
// in-flight = tile(t+1)'s 4 + tile(t+2)'s 4 -> drains t+1 (read next tile), keeps 4.
// Drain distance ~4-5 phases; never drains to 0 in the loop.
// Linear LDS is conflict-free: each wave b128-read covers a contiguous 1KB region
// (16 rows x 64B) = perfect 8 dwords/bank; stage dst = base + tid*16B (linear).
template <int OUT_BF16>
__global__ __launch_bounds__(256, 3) void gemm_nt_c4(const bf16_t* __restrict__ A,
                                                     const bf16_t* __restrict__ B,
                                                     const float* __restrict__ bias,
                                                     void* __restrict__ Cout,
                                                     int M, int N, int K) {
  __shared__ bf16_t SA[2 * 2 * 64 * 32];  // [buf][half][row][32]
  __shared__ bf16_t SB[2 * 2 * 64 * 32];
  const int tid = threadIdx.x;
  const int l = tid & 63, w = tid >> 6;
  const int l15 = l & 15, l4 = l >> 4;
  const int wm = w >> 1, wn = w & 1;
  const int nbm = M >> 7;
  const int nwg = gridDim.x;
  const int bid = blockIdx.x;
  const int wg = (bid & 7) * (nwg >> 3) + (bid >> 3);  // XCD chunks (nwg % 8 == 0)
  const int bn = wg / nbm, bm = wg % nbm;              // bm-minor: B-panel L2-resident

  // staging source (row = tid>>2 within a 64-row half, colblk = tid&3)
  const int srow = tid >> 2, scol = (tid & 3) << 3;
  const bf16_t* gA0 = A + (size_t)(bm * 128 + srow) * K + scol;
  const bf16_t* gA1 = gA0 + (size_t)64 * K;
  const bf16_t* gB0 = B + (size_t)(bn * 128 + srow) * K + scol;
  const bf16_t* gB1 = gB0 + (size_t)64 * K;
  // LDS staging dst offsets (elements): SA + (buf*2+half)*2048 + tid*8
  // read offsets: frag (half=wm/wn fixed per wave), row-in-half = f*16+l15, col l4*8
  const int aBase = wm * 2048 + l15 * 32 + l4 * 8;  // + buf*4096 + f*512
  const int bBase = wn * 2048 + l15 * 32 + l4 * 8;

  f32x4 acc[4][4] = {};
  bf16x8 aR[2], bR[4];

  const int nk = K >> 5;  // K=2048 -> 64 (even)

  auto stageB = [&](int t2, int buf) {
    stage16(gB0 + (size_t)t2 * 32, SB + buf * 4096 + tid * 8);
    stage16(gB1 + (size_t)t2 * 32, SB + buf * 4096 + 2048 + tid * 8);
  };
  auto stageA = [&](int t2, int buf) {
    stage16(gA0 + (size_t)t2 * 32, SA + buf * 4096 + tid * 8);
    stage16(gA1 + (size_t)t2 * 32, SA + buf * 4096 + 2048 + tid * 8);
  };

  auto TILE = [&](int buf, int t) {
    const int t2 = (t + 2 < nk) ? t + 2 : nk - 1;
    const bf16_t* SAb = SA + buf * 4096;
    const bf16_t* SBb = SB + buf * 4096;
    // ---- Ph1 ----
    aR[0] = *(const bf16x8*)(SAb + aBase);
    aR[1] = *(const bf16x8*)(SAb + aBase + 512);
    bR[0] = *(const bf16x8*)(SBb + bBase);
    bR[1] = *(const bf16x8*)(SBb + bBase + 512);
    BAR();
    LGKM0();
    PRIO1();
    acc[0][0] = MFMA16(aR[0], bR[0], acc[0][0]);
    acc[0][1] = MFMA16(aR[0], bR[1], acc[0][1]);
    acc[1][0] = MFMA16(aR[1], bR[0], acc[1][0]);
    acc[1][1] = MFMA16(aR[1], bR[1], acc[1][1]);
    PRIO0();
    BAR();
    // ---- Ph2 ----
    bR[2] = *(const bf16x8*)(SBb + bBase + 1024);
    bR[3] = *(const bf16x8*)(SBb + bBase + 1536);
    BAR();
    LGKM0();
    PRIO1();
    acc[0][2] = MFMA16(aR[0], bR[2], acc[0][2]);
    acc[0][3] = MFMA16(aR[0], bR[3], acc[0][3]);
    acc[1][2] = MFMA16(aR[1], bR[2], acc[1][2]);
    acc[1][3] = MFMA16(aR[1], bR[3], acc[1][3]);
    PRIO0();
    BAR();
    // ---- Ph3: reload aR with mi2,3; stage B(t+2) into this buf (B dead after Ph2) ----
    aR[0] = *(const bf16x8*)(SAb + aBase + 1024);
    aR[1] = *(const bf16x8*)(SAb + aBase + 1536);
    stageB(t2, buf);
    BAR();
    LGKM0();
    PRIO1();
    acc[2][2] = MFMA16(aR[0], bR[2], acc[2][2]);
    acc[2][3] = MFMA16(aR[0], bR[3], acc[2][3]);
    acc[3][2] = MFMA16(aR[1], bR[2], acc[3][2]);
    acc[3][3] = MFMA16(aR[1], bR[3], acc[3][3]);
    PRIO0();
    BAR();
    // ---- Ph4: stage A(t+2) (A dead after Ph3); one counted VMCNT per tile ----
    stageA(t2, buf);
    VMCNT(4);
    BAR();
    PRIO1();
    acc[2][0] = MFMA16(aR[0], bR[0], acc[2][0]);
    acc[2][1] = MFMA16(aR[0], bR[1], acc[2][1]);
    acc[3][0] = MFMA16(aR[1], bR[0], acc[3][0]);
    acc[3][1] = MFMA16(aR[1], bR[1], acc[3][1]);
    PRIO0();
    BAR();
  };

  // ---- prologue: stage tiles 0 (buf0) and 1 (buf1); drain tile0, keep tile1 ----
  stageB(0, 0);
  stageA(0, 0);
  stageB(1, 1);
  stageA(1, 1);
  VMCNT(4);
  BAR();

  for (int t = 0; t < nk; t += 2) {
    TILE(0, t);
    TILE(1, t + 1);
  }
  VMCNT(0);  // drain DMA before LDS is released to the next block

  // ---- epilogue ----
  const int rbase = bm * 128 + wm * 64 + (l4 << 2);
  const int cbase = bn * 128 + wn * 64 + l15;
#pragma unroll
  for (int ni = 0; ni < 4; ++ni) {
    float bv = bias[cbase + ni * 16];
#pragma unroll
    for (int mi = 0; mi < 4; ++mi)
#pragma unroll
      for (int r = 0; r < 4; ++r) {
        float v = acc[mi][ni][r] + bv;
        size_t off = (size_t)(rbase + mi * 16 + r) * N + (cbase + ni * 16);
        if (OUT_BF16) ((bf16_t*)Cout)[off] = (bf16_t)v;
        else ((float*)Cout)[off] = v;
      }
  }
}

// ---------------- causal flash attention (unchanged) ----------------
__global__ __launch_bounds__(256, 2) void attn_fwd(const bf16_t* __restrict__ qkv,
                                                   bf16_t* __restrict__ att) {
  __shared__ bf16_t Kt[64 * 128];
  __shared__ bf16_t Vt[128 * 64];
  __shared__ bf16_t Pw[4][16 * 64];

  int bid = blockIdx.x;
  int pair = bid >> 5, bh = bid & 31;
  int h = bh & 15, b = bh >> 4;
  int tid = threadIdx.x;
  int l = tid & 63, w = tid >> 6;
  int l15 = l & 15, l4 = l >> 4, l7 = l & 7;
  const size_t LD = 6144;
  const bf16_t* base = qkv + (size_t)b * 2048 * LD;

#pragma unroll 1
  for (int phase = 0; phase < 2; ++phase) {
    int qt = phase ? 31 - pair : pair;
    int q0 = qt << 6;
    int wq0 = q0 + w * 16;

    bf16x8 qf[4];
#pragma unroll
    for (int kk = 0; kk < 4; ++kk)
      qf[kk] = *(const bf16x8*)(base + (size_t)(wq0 + l15) * LD + h * 128 + kk * 32 + l4 * 8);

    f32x4 acc[8] = {};
    float mrow[4], lrow[4];
#pragma unroll
    for (int r = 0; r < 4; ++r) { mrow[r] = -1e30f; lrow[r] = 0.f; }

    int nkt = qt + 1;
    for (int kt = 0; kt < nkt; ++kt) {
      int kb = kt << 6;
      const bf16_t* vg = base + (size_t)kb * LD + 4096 + h * 128;
      us16x8 va[2], vb[2];
#pragma unroll
      for (int p = 0; p < 2; ++p) {
        int g = p * 256 + tid;
        int kv = (g >> 4) << 1;
        int d0 = (g & 15) << 3;
        va[p] = *(const us16x8*)(vg + (size_t)kv * LD + d0);
        vb[p] = *(const us16x8*)(vg + (size_t)(kv + 1) * LD + d0);
      }
      const bf16_t* kg = base + (size_t)kb * LD + 2048 + h * 128;
#pragma unroll
      for (int i = 0; i < 4; ++i) {
        int e = i * 256 + tid;
        int row = e >> 4, blk = e & 15;
        int src = (blk ^ (row & 7)) << 3;
        stage16(kg + (size_t)row * LD + src, Kt + e * 8);
      }
#pragma unroll
      for (int p = 0; p < 2; ++p) {
        int g = p * 256 + tid;
        int kv = (g >> 4) << 1;
        int d0 = (g & 15) << 3;
        int k8 = kv >> 3, kr = kv & 7;
#pragma unroll
        for (int j = 0; j < 8; ++j) {
          int d = d0 + j;
          int swz = k8 ^ ((d ^ (d >> 3)) & 7);
          unsigned pack = (unsigned)va[p][j] | ((unsigned)vb[p][j] << 16);
          *(unsigned*)(&Vt[d * 64 + swz * 8 + kr]) = pack;
        }
      }
      __syncthreads();

      {
        f32x4 s[4] = {};
        __builtin_amdgcn_s_setprio(1);
#pragma unroll
        for (int kk = 0; kk < 4; ++kk) {
          int blk = (kk * 4 + l4) ^ l7;
#pragma unroll
          for (int n = 0; n < 4; ++n) {
            bf16x8 kf = *(const bf16x8*)(Kt + (n * 16 + l15) * 128 + blk * 8);
            s[n] = MFMA16(qf[kk], kf, s[n]);
          }
        }
        __builtin_amdgcn_s_setprio(0);

        const float sc = 0.08838834764831845f;
        bool needMask = (kb + 63) > wq0;
        float scf[4];
#pragma unroll
        for (int r = 0; r < 4; ++r) {
          int q = wq0 + (l4 << 2) + r;
#pragma unroll
          for (int n = 0; n < 4; ++n) {
            float v = s[n][r] * sc;
            if (needMask && (kb + n * 16 + l15) > q) v = -1e30f;
            s[n][r] = v;
          }
          float mx = fmaxf(fmaxf(s[0][r], s[1][r]), fmaxf(s[2][r], s[3][r]));
          mx = fmaxf(mx, __shfl_xor(mx, 1));
          mx = fmaxf(mx, __shfl_xor(mx, 2));
          mx = fmaxf(mx, __shfl_xor(mx, 4));
          mx = fmaxf(mx, __shfl_xor(mx, 8));
          float mn = fmaxf(mrow[r], mx);
          float sf = __expf(mrow[r] - mn);
          mrow[r] = mn;
          scf[r] = sf;
          float rs = 0.f;
#pragma unroll
          for (int n = 0; n < 4; ++n) {
            float pv = __expf(s[n][r] - mn);
            s[n][r] = pv;
            rs += pv;
          }
          rs += __shfl_xor(rs, 1);
          rs += __shfl_xor(rs, 2);
          rs += __shfl_xor(rs, 4);
          rs += __shfl_xor(rs, 8);
          lrow[r] = lrow[r] * sf + rs;
        }
#pragma unroll
        for (int nd = 0; nd < 8; ++nd)
#pragma unroll
          for (int r = 0; r < 4; ++r)
            acc[nd][r] *= scf[r];
#pragma unroll
        for (int n = 0; n < 4; ++n) {
          int cb8 = n * 2 + (l15 >> 3);
#pragma unroll
          for (int r = 0; r < 4; ++r) {
            int row = (l4 << 2) + r;
            Pw[w][row * 64 + ((cb8 ^ (row & 7)) << 3) + l7] = (bf16_t)s[n][r];
          }
        }
        __builtin_amdgcn_s_setprio(1);
#pragma unroll
        for (int kk2 = 0; kk2 < 2; ++kk2) {
          bf16x8 pa = *(const bf16x8*)(&Pw[w][l15 * 64 + (((kk2 * 4 + l4) ^ l7) << 3)]);
#pragma unroll
          for (int nd = 0; nd < 8; ++nd) {
            int d = nd * 16 + l15;
            int swz = (kk2 * 4 + l4) ^ ((d ^ (d >> 3)) & 7);
            bf16x8 bv = *(const bf16x8*)(&Vt[d * 64 + swz * 8]);
            acc[nd] = MFMA16(pa, bv, acc[nd]);
          }
        }
        __builtin_amdgcn_s_setprio(0);
      }
      __syncthreads();
    }

#pragma unroll
    for (int r = 0; r < 4; ++r) {
      float inv = 1.0f / lrow[r];
      size_t ro = (size_t)(b * 2048 + wq0 + (l4 << 2) + r) * 2048 + h * 128;
#pragma unroll
      for (int nd = 0; nd < 8; ++nd)
        att[ro + nd * 16 + l15] = (bf16_t)(acc[nd][r] * inv);
    }
  }
}

// ---------------- launch ----------------
extern "C" void kernel_launch(void* const* d_in, const int* in_sizes, int n_in,
                              void* d_out, int out_size, void* d_ws, size_t ws_size,
                              hipStream_t stream) {
  (void)in_sizes; (void)n_in; (void)out_size; (void)ws_size;
  const float* x = (const float*)d_in[0];
  const float* w_attn = (const float*)d_in[1];
  const float* b_attn = (const float*)d_in[2];
  const float* w_proj = (const float*)d_in[3];
  const float* b_proj = (const float*)d_in[4];
  float* out = (float*)d_out;

  char* ws = (char*)d_ws;
  bf16_t* xb  = (bf16_t*)(ws);
  bf16_t* wab = (bf16_t*)(ws + 16777216);
  bf16_t* wpb = (bf16_t*)(ws + 41943040);
  bf16_t* qkv = (bf16_t*)(ws + 50331648);
  bf16_t* att = xb;  // xb dead after GEMM1

  cvt_f32_to_bf16<<<4096, 256, 0, stream>>>(x, xb, 1048576);
  cvt_f32_to_bf16<<<6144, 256, 0, stream>>>(w_attn, wab, 1572864);
  cvt_f32_to_bf16<<<2048, 256, 0, stream>>>(w_proj, wpb, 524288);

  // qkv = x @ w_attn^T + b_attn -> bf16 [4096, 6144]  (128^2 tiles: 32x48 = 1536 blocks)
  gemm_nt_c4<1><<<1536, 256, 0, stream>>>(xb, wab, b_attn, qkv, 4096, 6144, 2048);

  // causal flash attention -> att bf16 [4096, 2048]
  attn_fwd<<<512, 256, 0, stream>>>(qkv, att);

  // out = att @ w_proj^T + b_proj -> f32 [4096, 2048]  (128^2: 32x16 = 512 blocks)
  gemm_nt_c4<0><<<512, 256, 0, stream>>>(att, wpb, b_proj, out, 4096, 2048, 2048);
}